// Round 4
// baseline (373.774 us; speedup 1.0000x reference)
//
#include <hip/hip_runtime.h>
#include <hip/hip_bf16.h>

#define BATCH 512
#define NN 256

// ---------------------------------------------------------------------------
// Kernel 1: column means in fp32 replicating NUMPY PAIRWISE SUMMATION
// association bit-for-bit (numpy add.reduce binary-reduce inner loop over the
// reduction axis, pairwise_sum_FLOAT):
//   n=256 -> split 128+128 (blocks sequential);
//   each 128-block: r[t] = a[t] + a[8+t] + a[16+t] + ... + a[120+t]
//   (8 interleaved accumulators, m ascending), combined
//   ((r0+r1)+(r2+r3)) + ((r4+r5)+(r6+r7));
//   total = blockL + blockR; mean = total / 256 (exact pow2 scale).
// Additions only -> default strict FP keeps our explicit order.
// One wave per (batch, matrix); thread c4 owns 4 columns via float4 loads, so
// each k-step the wave reads a contiguous 1 KB row slice (coalesced).
// ---------------------------------------------------------------------------
__device__ __forceinline__ float4 f4add(float4 x, float4 y) {
  return make_float4(x.x + y.x, x.y + y.y, x.z + y.z, x.w + y.w);
}

__global__ __launch_bounds__(64) void col_means_kernel(
    const float* __restrict__ D1, const float* __restrict__ D2,
    float* __restrict__ am, float* __restrict__ bm) {
  const int b = blockIdx.x;
  const float* __restrict__ src = blockIdx.y ? D2 : D1;
  float* __restrict__ dst = blockIdx.y ? bm : am;
  const int c4 = threadIdx.x;  // 0..63

  const float* base = src + (size_t)b * (NN * NN) + 4 * c4;

  float4 half_sum[2];
#pragma unroll
  for (int h = 0; h < 2; ++h) {
    const float* hbase = base + (size_t)(h * 128) * NN;
    float4 r[8];
    // r[t] = a[t]
#pragma unroll
    for (int t = 0; t < 8; ++t) r[t] = *(const float4*)(hbase + (size_t)t * NN);
    // r[t] += a[8m + t], m = 1..15 ascending
    for (int m = 1; m < 16; ++m) {
#pragma unroll
      for (int t = 0; t < 8; ++t) {
        const float4 v = *(const float4*)(hbase + (size_t)(8 * m + t) * NN);
        r[t] = f4add(r[t], v);
      }
    }
    // ((r0+r1)+(r2+r3)) + ((r4+r5)+(r6+r7))
    const float4 s01 = f4add(r[0], r[1]);
    const float4 s23 = f4add(r[2], r[3]);
    const float4 s45 = f4add(r[4], r[5]);
    const float4 s67 = f4add(r[6], r[7]);
    half_sum[h] = f4add(f4add(s01, s23), f4add(s45, s67));
  }
  float4 tot = f4add(half_sum[0], half_sum[1]);
  const float inv = 1.0f / 256.0f;  // exact pow2 scale == np's /256.0
  tot.x *= inv; tot.y *= inv; tot.z *= inv; tot.w *= inv;
  *(float4*)(dst + (size_t)b * NN + 4 * c4) = tot;
}

// ---------------------------------------------------------------------------
// Kernel 2: exact stable lexsort via ranking (fp32 keys). Thread i counts how
// many j have (type_j, value_j, j) < (type_i, value_i, i) — a strict total
// order, so ranks are a permutation and exactly reproduce stable np.lexsort
// (type primary, value secondary, index tie-break — handles exact fp32 ties).
// ord1[rank] = atom, ord2[rank] = slot, perm[ord2[k]] = ord1[k].
// LDS reads are wave-broadcast (all lanes read the same j) — conflict-free.
// ---------------------------------------------------------------------------
__global__ __launch_bounds__(256) void rank_perm_kernel(
    const float* __restrict__ am, const float* __restrict__ bm,
    const int* __restrict__ t1, const int* __restrict__ t2,
    int* __restrict__ perm, float* __restrict__ types_out) {
  const int b = blockIdx.x;
  const int tid = threadIdx.x;

  __shared__ float va[NN];
  __shared__ int ta[NN];
  __shared__ int ord1[NN];
  __shared__ int ord2[NN];
  __shared__ int plds[NN];

  // ---- side A: rank (t1, a, idx) ----
  va[tid] = am[b * NN + tid];
  ta[tid] = t1[b * NN + tid];
  __syncthreads();
  {
    const float vi = va[tid];
    const int ti = ta[tid];
    int r = 0;
#pragma unroll 4
    for (int j = 0; j < NN; ++j) {
      const int tj = ta[j];
      const float vj = va[j];
      const bool less =
          (tj < ti) || (tj == ti && (vj < vi || (vj == vi && j < tid)));
      r += less ? 1 : 0;
    }
    ord1[r] = tid;
  }
  __syncthreads();

  // ---- side B: rank (t2, b, idx) ----
  va[tid] = bm[b * NN + tid];
  ta[tid] = t2[b * NN + tid];
  __syncthreads();
  {
    const float vi = va[tid];
    const int ti = ta[tid];
    int r = 0;
#pragma unroll 4
    for (int j = 0; j < NN; ++j) {
      const int tj = ta[j];
      const float vj = va[j];
      const bool less =
          (tj < ti) || (tj == ti && (vj < vi || (vj == vi && j < tid)));
      r += less ? 1 : 0;
    }
    ord2[r] = tid;
  }
  __syncthreads();

  // perm[ord2[k]] = ord1[k]
  plds[ord2[tid]] = ord1[tid];
  __syncthreads();

  perm[b * NN + tid] = plds[tid];
  types_out[b * NN + tid] = (float)t1[b * NN + plds[tid]];
}

// ---------------------------------------------------------------------------
// Kernel 3: out[b,i,j] = D1[b, perm[i], perm[j]].
// One block handles 4 output rows of one batch (one wave per row).
// Source row staged coalesced (float4) into LDS; column permutation done as
// LDS gather (random perm -> low-way bank aliasing, ~free); float4 stores.
// ---------------------------------------------------------------------------
__global__ __launch_bounds__(256) void reorder_kernel(
    const float* __restrict__ D1, const int* __restrict__ perm,
    float* __restrict__ out) {
  const int b = blockIdx.x >> 6;
  const int ig = blockIdx.x & 63;
  const int tid = threadIdx.x;
  const int lane = tid & 63;
  const int w = tid >> 6;

  __shared__ int plds[NN];
  __shared__ float4 rows[4][64];

  plds[tid] = perm[b * NN + tid];
  __syncthreads();

  const int i = ig * 4 + w;
  const int pi = plds[i];
  const float* rsrc = D1 + ((size_t)b * NN + pi) * NN;
  rows[w][lane] = *(const float4*)(rsrc + 4 * lane);
  __syncthreads();

  const float* rf = (const float*)&rows[w][0];
  const int j0 = 4 * lane;
  float4 o;
  o.x = rf[plds[j0 + 0]];
  o.y = rf[plds[j0 + 1]];
  o.z = rf[plds[j0 + 2]];
  o.w = rf[plds[j0 + 3]];
  *(float4*)(out + ((size_t)b * NN + i) * NN + j0) = o;
}

extern "C" void kernel_launch(void* const* d_in, const int* in_sizes, int n_in,
                              void* d_out, int out_size, void* d_ws, size_t ws_size,
                              hipStream_t stream) {
  const float* D1 = (const float*)d_in[0];
  const float* D2 = (const float*)d_in[1];
  const int* t1 = (const int*)d_in[2];
  const int* t2 = (const int*)d_in[3];

  float* out = (float*)d_out;                       // [B,N,N] fp32
  float* types_out = out + (size_t)BATCH * NN * NN; // [B,N] written as fp32

  // workspace: a-means f32 [B*N], b-means f32 [B*N], perm i32 [B*N]
  float* am = (float*)d_ws;
  float* bm = am + (size_t)BATCH * NN;
  int* perm = (int*)(bm + (size_t)BATCH * NN);

  col_means_kernel<<<dim3(BATCH, 2), 64, 0, stream>>>(D1, D2, am, bm);
  rank_perm_kernel<<<BATCH, 256, 0, stream>>>(am, bm, t1, t2, perm, types_out);
  reorder_kernel<<<BATCH * 64, 256, 0, stream>>>(D1, perm, out);
}